// Round 1
// baseline (641.036 us; speedup 1.0000x reference)
//
#include <hip/hip_runtime.h>

#define D_IN 256
#define H1   128
#define H2   64
#define RTILE 16
#define NBLK  256   // 4096 rows / 16 per stream

// unified transposed weight layout: wt[(h*9 + j)*Din + d]
//   j==0 -> base weight, j==1+k -> spline weight for grid k
#define N1 (H1*9*D_IN)   // 294912
#define N2 (H2*9*H1)     // 73728

__global__ __launch_bounds__(256) void prep_all(
    const float* __restrict__ bw1x, const float* __restrict__ sw1x,
    const float* __restrict__ bb1x, const float* __restrict__ sb1x,
    const float* __restrict__ bw2x, const float* __restrict__ sw2x,
    const float* __restrict__ bb2x, const float* __restrict__ sb2x,
    const float* __restrict__ bw1y, const float* __restrict__ sw1y,
    const float* __restrict__ bb1y, const float* __restrict__ sb1y,
    const float* __restrict__ bw2y, const float* __restrict__ sw2y,
    const float* __restrict__ bb2y, const float* __restrict__ sb2y,
    float* __restrict__ wt1x, float* __restrict__ wt1y,
    float* __restrict__ wt2x, float* __restrict__ wt2y,
    float* __restrict__ b1x, float* __restrict__ b1y,
    float* __restrict__ b2x, float* __restrict__ b2y)
{
  int i = blockIdx.x * 256 + threadIdx.x;
  if (i < N1) {
    int d = i % D_IN; int hj = i / D_IN; int j = hj % 9; int h = hj / 9;
    wt1x[i] = (j == 0) ? bw1x[h*D_IN + d] : sw1x[(h*D_IN + d)*8 + (j-1)];
  } else if (i < 2*N1) {
    int i2 = i - N1;
    int d = i2 % D_IN; int hj = i2 / D_IN; int j = hj % 9; int h = hj / 9;
    wt1y[i2] = (j == 0) ? bw1y[h*D_IN + d] : sw1y[(h*D_IN + d)*8 + (j-1)];
  } else if (i < 2*N1 + N2) {
    int i2 = i - 2*N1;
    int d = i2 % H1; int hj = i2 / H1; int j = hj % 9; int h = hj / 9;
    wt2x[i2] = (j == 0) ? bw2x[h*H1 + d] : sw2x[(h*H1 + d)*8 + (j-1)];
  } else if (i < 2*N1 + 2*N2) {
    int i2 = i - (2*N1 + N2);
    int d = i2 % H1; int hj = i2 / H1; int j = hj % 9; int h = hj / 9;
    wt2y[i2] = (j == 0) ? bw2y[h*H1 + d] : sw2y[(h*H1 + d)*8 + (j-1)];
  } else {
    int i2 = i - (2*N1 + 2*N2);
    if (i2 < 128)      b1x[i2]     = bb1x[i2]     + sb1x[i2];
    else if (i2 < 256) b1y[i2-128] = bb1y[i2-128] + sb1y[i2-128];
    else if (i2 < 320) b2x[i2-256] = bb2x[i2-256] + sb2x[i2-256];
    else if (i2 < 384) b2y[i2-320] = bb2y[i2-320] + sb2y[i2-320];
  }
}

__global__ __launch_bounds__(256, 2) void fused_kernel(
    const float* __restrict__ Xx, const float* __restrict__ Xy,
    const float* __restrict__ wt1x, const float* __restrict__ wt1y,
    const float* __restrict__ wt2x, const float* __restrict__ wt2y,
    const float* __restrict__ b1x_, const float* __restrict__ b1y_,
    const float* __restrict__ b2x_, const float* __restrict__ b2y_,
    const float* __restrict__ finw,
    float* __restrict__ partial)
{
  __shared__ float xs[RTILE*256];     // 16 KB
  __shared__ float fe[9*RTILE*68];    // 38.25 KB, plane j at (j*RTILE+r)*68 + d
  __shared__ float h1s[RTILE*129];    // 8.06 KB
  __shared__ float red[256];

  const int t   = threadIdx.x;
  const int sid = blockIdx.x >> 8;   // 0 = x stream, 1 = y stream
  const int rb  = blockIdx.x & 255;

  const float* X   = sid ? Xy   : Xx;
  const float* wt1 = sid ? wt1y : wt1x;
  const float* wt2 = sid ? wt2y : wt2x;
  const float* b1  = sid ? b1y_ : b1x_;
  const float* b2  = sid ? b2y_ : b2x_;

  // ---- load 16x256 x-tile ----
  {
    const float4* Xg = (const float4*)(X + (size_t)rb * (RTILE*256));
    float4* xs4 = (float4*)xs;
    #pragma unroll
    for (int i = 0; i < 4; ++i) xs4[t + i*256] = Xg[t + i*256];
  }
  __syncthreads();

  const int tx = t & 31;   // 32 output groups
  const int tz = t >> 5;   // rows tz and tz+8

  const float INVH = 1.75f;  // 1 / (4/7)

  // ================= layer 1: 256 dims -> 128 =================
  float acc0[4], acc1[4];
  #pragma unroll
  for (int o = 0; o < 4; ++o) { float b = b1[tx*4 + o]; acc0[o] = b; acc1[o] = b; }

  #pragma unroll 1
  for (int c = 0; c < 4; ++c) {
    const int D0 = c * 64;
    // cooperative feats: 16 rows x 64 dims x 9 planes
    #pragma unroll
    for (int i = 0; i < 4; ++i) {
      int p = t + i*256;
      int r = p >> 6, dd = p & 63;
      float xv = xs[r*256 + D0 + dd];
      float sg = 1.0f / (1.0f + __expf(-xv));
      fe[r*68 + dd] = xv * sg;                        // j = 0 (silu)
      #pragma unroll
      for (int k = 0; k < 8; ++k) {
        float g = -2.0f + (float)k * (4.0f/7.0f);
        float z = (xv - g) * INVH;
        fe[((1+k)*RTILE + r)*68 + dd] = __expf(-z*z); // j = 1+k (rbf)
      }
    }
    __syncthreads();

    #pragma unroll 1
    for (int j = 0; j < 9; ++j) {
      const float* wrow = wt1 + (size_t)(tx*4*9 + j)*256 + D0;  // o stride 9*256
      const float* fb   = fe + (j*RTILE + tz)*68;
      #pragma unroll
      for (int d4 = 0; d4 < 16; ++d4) {
        float4 fA = *(const float4*)(fb + d4*4);
        float4 fB = *(const float4*)(fb + 8*68 + d4*4);
        #pragma unroll
        for (int o = 0; o < 4; ++o) {
          float4 w = *(const float4*)(wrow + o*(9*256) + d4*4);
          acc0[o] += fA.x*w.x + fA.y*w.y + fA.z*w.z + fA.w*w.w;
          acc1[o] += fB.x*w.x + fB.y*w.y + fB.z*w.z + fB.w*w.w;
        }
      }
    }
    __syncthreads();
  }

  #pragma unroll
  for (int o = 0; o < 4; ++o) {
    h1s[tz*129 + tx*4 + o]     = acc0[o];
    h1s[(tz+8)*129 + tx*4 + o] = acc1[o];
  }
  __syncthreads();

  // ================= layer 2: 128 dims -> 64 =================
  float a20[2], a21[2];
  #pragma unroll
  for (int o = 0; o < 2; ++o) { float b = b2[tx*2 + o]; a20[o] = b; a21[o] = b; }

  #pragma unroll 1
  for (int c = 0; c < 2; ++c) {
    const int D0 = c * 64;
    #pragma unroll
    for (int i = 0; i < 4; ++i) {
      int p = t + i*256;
      int r = p >> 6, dd = p & 63;
      float xv = h1s[r*129 + D0 + dd];
      float sg = 1.0f / (1.0f + __expf(-xv));
      fe[r*68 + dd] = xv * sg;
      #pragma unroll
      for (int k = 0; k < 8; ++k) {
        float g = -2.0f + (float)k * (4.0f/7.0f);
        float z = (xv - g) * INVH;
        fe[((1+k)*RTILE + r)*68 + dd] = __expf(-z*z);
      }
    }
    __syncthreads();

    #pragma unroll 1
    for (int j = 0; j < 9; ++j) {
      const float* wrow = wt2 + (size_t)(tx*2*9 + j)*128 + D0;  // o stride 9*128
      const float* fb   = fe + (j*RTILE + tz)*68;
      #pragma unroll
      for (int d4 = 0; d4 < 16; ++d4) {
        float4 fA = *(const float4*)(fb + d4*4);
        float4 fB = *(const float4*)(fb + 8*68 + d4*4);
        #pragma unroll
        for (int o = 0; o < 2; ++o) {
          float4 w = *(const float4*)(wrow + o*(9*128) + d4*4);
          a20[o] += fA.x*w.x + fA.y*w.y + fA.z*w.z + fA.w*w.w;
          a21[o] += fB.x*w.x + fB.y*w.y + fB.z*w.z + fB.w*w.w;
        }
      }
    }
    __syncthreads();
  }

  // ---- final dot with this stream's half of final_w, block reduce ----
  const float* wf = finw + sid*64;
  float pz = 0.f;
  #pragma unroll
  for (int o = 0; o < 2; ++o)
    pz += (a20[o] + a21[o]) * wf[tx*2 + o];

  red[t] = pz;
  __syncthreads();
  #pragma unroll 1
  for (int s = 128; s > 0; s >>= 1) {
    if (t < s) red[t] += red[t + s];
    __syncthreads();
  }
  if (t == 0) partial[sid*256 + rb] = red[0];
}

__global__ __launch_bounds__(256) void reduce_kernel(
    const float* __restrict__ partial, const float* __restrict__ finb,
    float* __restrict__ out)
{
  int t = threadIdx.x;          // 256 threads: 4 waves, one batch each
  int b = t >> 6, i = t & 63;
  float v = partial[b*64 + i] + partial[256 + b*64 + i];
  #pragma unroll
  for (int off = 32; off > 0; off >>= 1) v += __shfl_down(v, off, 64);
  if (i == 0) out[b] = finb[0] + v * (1.0f/1024.0f);
}

extern "C" void kernel_launch(void* const* d_in, const int* in_sizes, int n_in,
                              void* d_out, int out_size, void* d_ws, size_t ws_size,
                              hipStream_t stream)
{
  (void)in_sizes; (void)n_in; (void)out_size; (void)ws_size;
  const float* x    = (const float*)d_in[0];
  const float* y    = (const float*)d_in[1];
  const float* bw1x = (const float*)d_in[2];
  const float* bb1x = (const float*)d_in[3];
  const float* sw1x = (const float*)d_in[4];
  const float* sb1x = (const float*)d_in[5];
  const float* bw2x = (const float*)d_in[6];
  const float* bb2x = (const float*)d_in[7];
  const float* sw2x = (const float*)d_in[8];
  const float* sb2x = (const float*)d_in[9];
  const float* bw1y = (const float*)d_in[10];
  const float* bb1y = (const float*)d_in[11];
  const float* sw1y = (const float*)d_in[12];
  const float* sb1y = (const float*)d_in[13];
  const float* bw2y = (const float*)d_in[14];
  const float* bb2y = (const float*)d_in[15];
  const float* sw2y = (const float*)d_in[16];
  const float* sb2y = (const float*)d_in[17];
  const float* finw = (const float*)d_in[18];
  const float* finb = (const float*)d_in[19];

  float* ws = (float*)d_ws;
  float* wt1x = ws;               // 294912
  float* wt1y = wt1x + N1;
  float* wt2x = wt1y + N1;        // 73728
  float* wt2y = wt2x + N2;
  float* b1x  = wt2y + N2;        // 128
  float* b1y  = b1x + 128;
  float* b2x  = b1y + 128;        // 64
  float* b2y  = b2x + 64;
  float* partial = b2y + 64;      // 512

  int prep_blocks = (2*N1 + 2*N2 + 384 + 255) / 256;
  hipLaunchKernelGGL(prep_all, dim3(prep_blocks), dim3(256), 0, stream,
                     bw1x, sw1x, bb1x, sb1x, bw2x, sw2x, bb2x, sb2x,
                     bw1y, sw1y, bb1y, sb1y, bw2y, sw2y, bb2y, sb2y,
                     wt1x, wt1y, wt2x, wt2y, b1x, b1y, b2x, b2y);

  hipLaunchKernelGGL(fused_kernel, dim3(512), dim3(256), 0, stream,
                     x, y, wt1x, wt1y, wt2x, wt2y, b1x, b1y, b2x, b2y,
                     finw, partial);

  hipLaunchKernelGGL(reduce_kernel, dim3(1), dim3(256), 0, stream,
                     partial, finb, (float*)d_out);
}

// Round 2
// 140.916 us; speedup vs baseline: 4.5491x; 4.5491x over previous
//
#include <hip/hip_runtime.h>

#define D1 256
#define H1 128
#define H2 64
#define RT 16          // rows per block
#define FEP 40         // fe row stride (floats) -> 160B, 16B aligned
#define H1P 136        // h1s row stride (floats), 16B aligned

// transposed unified weights: wT[(j*D + d)*O + o], j=0 base, j=1+k spline grid k
#define N1T (9*D1*H1)  // 294912
#define N2T (9*H1*H2)  // 73728

__global__ __launch_bounds__(256) void prep_all(
    const float* __restrict__ bw1x, const float* __restrict__ sw1x,
    const float* __restrict__ bb1x, const float* __restrict__ sb1x,
    const float* __restrict__ bw2x, const float* __restrict__ sw2x,
    const float* __restrict__ bb2x, const float* __restrict__ sb2x,
    const float* __restrict__ bw1y, const float* __restrict__ sw1y,
    const float* __restrict__ bb1y, const float* __restrict__ sb1y,
    const float* __restrict__ bw2y, const float* __restrict__ sw2y,
    const float* __restrict__ bb2y, const float* __restrict__ sb2y,
    float* __restrict__ w1xT, float* __restrict__ w1yT,
    float* __restrict__ w2xT, float* __restrict__ w2yT,
    float* __restrict__ b1x, float* __restrict__ b1y,
    float* __restrict__ b2x, float* __restrict__ b2y)
{
  int i = blockIdx.x * 256 + threadIdx.x;
  if (i < N1T) {
    int o = i & 127; int rest = i >> 7; int d = rest & 255; int j = rest >> 8;
    w1xT[i] = (j == 0) ? bw1x[o*256 + d] : sw1x[o*2048 + d*8 + (j-1)];
  } else if (i < 2*N1T) {
    int i2 = i - N1T;
    int o = i2 & 127; int rest = i2 >> 7; int d = rest & 255; int j = rest >> 8;
    w1yT[i2] = (j == 0) ? bw1y[o*256 + d] : sw1y[o*2048 + d*8 + (j-1)];
  } else if (i < 2*N1T + N2T) {
    int i2 = i - 2*N1T;
    int o = i2 & 63; int rest = i2 >> 6; int d = rest & 127; int j = rest >> 7;
    w2xT[i2] = (j == 0) ? bw2x[o*128 + d] : sw2x[o*1024 + d*8 + (j-1)];
  } else if (i < 2*N1T + 2*N2T) {
    int i2 = i - (2*N1T + N2T);
    int o = i2 & 63; int rest = i2 >> 6; int d = rest & 127; int j = rest >> 7;
    w2yT[i2] = (j == 0) ? bw2y[o*128 + d] : sw2y[o*1024 + d*8 + (j-1)];
  } else {
    int i2 = i - (2*N1T + 2*N2T);
    if (i2 < 128)      b1x[i2]     = bb1x[i2]     + sb1x[i2];
    else if (i2 < 256) b1y[i2-128] = bb1y[i2-128] + sb1y[i2-128];
    else if (i2 < 320) b2x[i2-256] = bb2x[i2-256] + sb2x[i2-256];
    else if (i2 < 384) b2y[i2-320] = bb2y[i2-320] + sb2y[i2-320];
  }
}

__global__ __launch_bounds__(256, 2) void fused_kernel(
    const float* __restrict__ Xx, const float* __restrict__ Xy,
    const float* __restrict__ w1xT, const float* __restrict__ w1yT,
    const float* __restrict__ w2xT, const float* __restrict__ w2yT,
    const float* __restrict__ b1x_, const float* __restrict__ b1y_,
    const float* __restrict__ b2x_, const float* __restrict__ b2y_,
    const float* __restrict__ finw, float* __restrict__ partial)
{
  __shared__ float fe[9*RT*FEP];     // 23040 B, 9 feature planes for current chunk
  __shared__ float h1s[RT*H1P];      // 8704 B
  __shared__ float wbuf[2][4096];    // 2 x 16 KB weight slabs
  // total 64512 B static LDS -> 2 blocks/CU

  const int t   = threadIdx.x;
  const int sid = blockIdx.x >> 8;   // 0=x, 1=y
  const int rb  = blockIdx.x & 255;

  const float* X  = sid ? Xy   : Xx;
  const float* w1 = sid ? w1yT : w1xT;
  const float* w2 = sid ? w2yT : w2xT;
  const float* b1 = sid ? b1y_ : b1x_;
  const float* b2 = sid ? b2y_ : b2x_;

  // lane map: wave has 8 tx-groups x 8 tz-groups -> 8-way LDS broadcast both sides
  const int tx = t >> 3;   // 32 out-groups
  const int tz = t & 7;    // rows tz and tz+8

  const float INVH = 1.75f;  // 1 / (4/7)
  const size_t xbase = (size_t)(rb * RT) * D1;

  // ---- prologue: stage L1 slab (c=0, j=0) into wbuf[0] ----
  {
    float4 s0 = *(const float4*)(w1 + 4*t);
    float4 s1 = *(const float4*)(w1 + 4*t + 1024);
    float4 s2 = *(const float4*)(w1 + 4*t + 2048);
    float4 s3 = *(const float4*)(w1 + 4*t + 3072);
    *(float4*)(wbuf[0] + 4*t)        = s0;
    *(float4*)(wbuf[0] + 4*t + 1024) = s1;
    *(float4*)(wbuf[0] + 4*t + 2048) = s2;
    *(float4*)(wbuf[0] + 4*t + 3072) = s3;
  }

  // ================= layer 1: K = 256 dims x 9 planes -> 128 outs =============
  float acc0[4], acc1[4];
  #pragma unroll
  for (int o = 0; o < 4; ++o) { float b = b1[tx*4 + o]; acc0[o] = b; acc1[o] = b; }

  int cur = 0, c = 0, j = 0;
  #pragma unroll 1
  for (int s = 0; s < 72; ++s) {
    __syncthreads();                 // wbuf[cur] staged, fe free for reuse

    if (j == 0) {                    // compute 9 feature planes for chunk c
      #pragma unroll
      for (int i = 0; i < 2; ++i) {
        int p = t + i*256;
        int r = p >> 5, dd = p & 31;
        float xv = X[xbase + (size_t)r*D1 + c*32 + dd];
        float e  = __expf(-xv);
        fe[r*FEP + dd] = xv / (1.0f + e);            // silu, plane 0
        #pragma unroll
        for (int k = 0; k < 8; ++k) {
          float g = -2.0f + (float)k * (4.0f/7.0f);
          float z = (xv - g) * INVH;
          fe[((1+k)*RT + r)*FEP + dd] = __expf(-z*z);
        }
      }
      __syncthreads();
    }

    // issue next-slab loads (T14: write after compute)
    float4 st0, st1, st2, st3;
    bool nx4 = (s < 71);
    {
      const float* nsrc;
      if (nx4) {
        int jn = j + 1, cn = c; if (jn == 9) { jn = 0; cn = c + 1; }
        nsrc = w1 + jn*32768 + cn*4096;
      } else nsrc = w2;              // cross-layer prefetch: L2 slab (0,0)
      st0 = *(const float4*)(nsrc + 4*t);
      st1 = *(const float4*)(nsrc + 4*t + 1024);
      if (nx4) {
        st2 = *(const float4*)(nsrc + 4*t + 2048);
        st3 = *(const float4*)(nsrc + 4*t + 3072);
      }
    }

    // compute: slab (c, j) -- rank-1 updates, 32 FMA per d4 group
    const float* wsl = wbuf[cur];
    const float* fb  = fe + (j*RT + tz)*FEP;
    #pragma unroll
    for (int g = 0; g < 8; ++g) {
      float4 fA = *(const float4*)(fb + g*4);
      float4 fB = *(const float4*)(fb + 8*FEP + g*4);
      #pragma unroll
      for (int dd = 0; dd < 4; ++dd) {
        float4 w = *(const float4*)(wsl + (g*4 + dd)*H1 + tx*4);
        float fa  = (&fA.x)[dd];
        float fbv = (&fB.x)[dd];
        acc0[0] += fa*w.x;  acc0[1] += fa*w.y;  acc0[2] += fa*w.z;  acc0[3] += fa*w.w;
        acc1[0] += fbv*w.x; acc1[1] += fbv*w.y; acc1[2] += fbv*w.z; acc1[3] += fbv*w.w;
      }
    }

    // late LDS write of staged slab
    {
      float* wd = wbuf[cur ^ 1];
      *(float4*)(wd + 4*t)        = st0;
      *(float4*)(wd + 4*t + 1024) = st1;
      if (nx4) {
        *(float4*)(wd + 4*t + 2048) = st2;
        *(float4*)(wd + 4*t + 3072) = st3;
      }
    }
    cur ^= 1;
    if (++j == 9) { j = 0; ++c; }
  }

  // h1 (with bias) -> LDS
  *(float4*)(h1s + tz*H1P + tx*4)     = make_float4(acc0[0], acc0[1], acc0[2], acc0[3]);
  *(float4*)(h1s + (tz+8)*H1P + tx*4) = make_float4(acc1[0], acc1[1], acc1[2], acc1[3]);

  // ================= layer 2: K = 128 dims x 9 planes -> 64 outs ==============
  float a20[2], a21[2];
  #pragma unroll
  for (int o = 0; o < 2; ++o) { float b = b2[tx*2 + o]; a20[o] = b; a21[o] = b; }

  c = 0; j = 0;
  #pragma unroll 1
  for (int s = 0; s < 36; ++s) {
    __syncthreads();

    if (j == 0) {
      #pragma unroll
      for (int i = 0; i < 2; ++i) {
        int p = t + i*256;
        int r = p >> 5, dd = p & 31;
        float xv = h1s[r*H1P + c*32 + dd];
        float e  = __expf(-xv);
        fe[r*FEP + dd] = xv / (1.0f + e);
        #pragma unroll
        for (int k = 0; k < 8; ++k) {
          float g = -2.0f + (float)k * (4.0f/7.0f);
          float z = (xv - g) * INVH;
          fe[((1+k)*RT + r)*FEP + dd] = __expf(-z*z);
        }
      }
      __syncthreads();
    }

    float4 st0, st1; bool hasn = (s < 35);
    if (hasn) {
      int jn = j + 1, cn = c; if (jn == 9) { jn = 0; cn = c + 1; }
      const float* nsrc = w2 + jn*8192 + cn*2048;
      st0 = *(const float4*)(nsrc + 4*t);
      st1 = *(const float4*)(nsrc + 4*t + 1024);
    }

    const float* wsl = wbuf[cur];
    const float* fb  = fe + (j*RT + tz)*FEP;
    #pragma unroll
    for (int g = 0; g < 8; ++g) {
      float4 fA = *(const float4*)(fb + g*4);
      float4 fB = *(const float4*)(fb + 8*FEP + g*4);
      #pragma unroll
      for (int dd = 0; dd < 4; ++dd) {
        float2 w = *(const float2*)(wsl + (g*4 + dd)*H2 + tx*2);
        float fa  = (&fA.x)[dd];
        float fbv = (&fB.x)[dd];
        a20[0] += fa*w.x;  a20[1] += fa*w.y;
        a21[0] += fbv*w.x; a21[1] += fbv*w.y;
      }
    }

    if (hasn) {
      float* wd = wbuf[cur ^ 1];
      *(float4*)(wd + 4*t)        = st0;
      *(float4*)(wd + 4*t + 1024) = st1;
    }
    cur ^= 1;
    if (++j == 9) { j = 0; ++c; }
  }

  // ---- final dot + block reduce (reuse fe as scratch) ----
  const float* wf = finw + sid*64;
  float pz = (a20[0] + a21[0]) * wf[tx*2] + (a20[1] + a21[1]) * wf[tx*2 + 1];

  __syncthreads();
  float* red = fe;
  red[t] = pz;
  __syncthreads();
  #pragma unroll 1
  for (int sft = 128; sft > 0; sft >>= 1) {
    if (t < sft) red[t] += red[t + sft];
    __syncthreads();
  }
  if (t == 0) partial[sid*256 + rb] = red[0];
}

__global__ __launch_bounds__(256) void reduce_kernel(
    const float* __restrict__ partial, const float* __restrict__ finb,
    float* __restrict__ out)
{
  int t = threadIdx.x;
  int b = t >> 6, i = t & 63;
  float v = partial[b*64 + i] + partial[256 + b*64 + i];
  #pragma unroll
  for (int off = 32; off > 0; off >>= 1) v += __shfl_down(v, off, 64);
  if (i == 0) out[b] = finb[0] + v * (1.0f/1024.0f);
}

extern "C" void kernel_launch(void* const* d_in, const int* in_sizes, int n_in,
                              void* d_out, int out_size, void* d_ws, size_t ws_size,
                              hipStream_t stream)
{
  (void)in_sizes; (void)n_in; (void)out_size; (void)ws_size;
  const float* x    = (const float*)d_in[0];
  const float* y    = (const float*)d_in[1];
  const float* bw1x = (const float*)d_in[2];
  const float* bb1x = (const float*)d_in[3];
  const float* sw1x = (const float*)d_in[4];
  const float* sb1x = (const float*)d_in[5];
  const float* bw2x = (const float*)d_in[6];
  const float* bb2x = (const float*)d_in[7];
  const float* sw2x = (const float*)d_in[8];
  const float* sb2x = (const float*)d_in[9];
  const float* bw1y = (const float*)d_in[10];
  const float* bb1y = (const float*)d_in[11];
  const float* sw1y = (const float*)d_in[12];
  const float* sb1y = (const float*)d_in[13];
  const float* bw2y = (const float*)d_in[14];
  const float* bb2y = (const float*)d_in[15];
  const float* sw2y = (const float*)d_in[16];
  const float* sb2y = (const float*)d_in[17];
  const float* finw = (const float*)d_in[18];
  const float* finb = (const float*)d_in[19];

  float* ws = (float*)d_ws;
  float* w1xT = ws;               // 294912
  float* w1yT = w1xT + N1T;
  float* w2xT = w1yT + N1T;       // 73728
  float* w2yT = w2xT + N2T;
  float* b1x  = w2yT + N2T;       // 128
  float* b1y  = b1x + 128;
  float* b2x  = b1y + 128;        // 64
  float* b2y  = b2x + 64;
  float* partial = b2y + 64;      // 512

  int prep_blocks = (2*N1T + 2*N2T + 384 + 255) / 256;
  hipLaunchKernelGGL(prep_all, dim3(prep_blocks), dim3(256), 0, stream,
                     bw1x, sw1x, bb1x, sb1x, bw2x, sw2x, bb2x, sb2x,
                     bw1y, sw1y, bb1y, sb1y, bw2y, sw2y, bb2y, sb2y,
                     w1xT, w1yT, w2xT, w2yT, b1x, b1y, b2x, b2y);

  hipLaunchKernelGGL(fused_kernel, dim3(512), dim3(256), 0, stream,
                     x, y, w1xT, w1yT, w2xT, w2yT, b1x, b1y, b2x, b2y,
                     finw, partial);

  hipLaunchKernelGGL(reduce_kernel, dim3(1), dim3(256), 0, stream,
                     partial, finb, (float*)d_out);
}